// Round 5
// baseline (916.757 us; speedup 1.0000x reference)
//
#include <hip/hip_runtime.h>

#define NNODES 100000
#define DIM 128
#define BROWS 256               // rows per bucket
#define NB ((NNODES + BROWS - 1) / BROWS)   // 391 buckets
#define BCAP 5120               // capacity per bucket (mean 4092, sd 64 -> +16 sigma)

__device__ __forceinline__ float f4c(const float4& v, int q) {
    switch (q) { case 0: return v.x; case 1: return v.y; case 2: return v.z; }
    return v.w;
}

__device__ __forceinline__ unsigned int pack_bf16x2(float lo, float hi) {
    unsigned int ul = __float_as_uint(lo);
    unsigned int uh = __float_as_uint(hi);
    ul = (ul + 0x7fffu + ((ul >> 16) & 1u)) >> 16;   // RNE
    uh = (uh + 0x7fffu + ((uh >> 16) & 1u)) & 0xffff0000u;
    return uh | ul;
}

__device__ __forceinline__ void unpack_bf16x8(uint4 v, float* f) {
    f[0] = __uint_as_float(v.x << 16); f[1] = __uint_as_float(v.x & 0xffff0000u);
    f[2] = __uint_as_float(v.y << 16); f[3] = __uint_as_float(v.y & 0xffff0000u);
    f[4] = __uint_as_float(v.z << 16); f[5] = __uint_as_float(v.z & 0xffff0000u);
    f[6] = __uint_as_float(v.w << 16); f[7] = __uint_as_float(v.w & 0xffff0000u);
}

// ---------------- Dense GEMM: Yb(bf16) = A @ W + b ----------------
template <bool IN_BF16>
__global__ __launch_bounds__(256, 2) void gemm_tile(const void* __restrict__ Ain,
                                                    const float* __restrict__ W,
                                                    const float* __restrict__ bias,
                                                    unsigned short* __restrict__ Yb, int n) {
    __shared__ float as[128 * 36];
    __shared__ float bs[32 * 128];
    const int t = threadIdx.x;
    const int tx = t & 15, ty = t >> 4;
    const int row0 = blockIdx.x * 128;
    const int r_lo = ty * 4;
    const int c_lo = tx * 4;

    float acc[8][8];
    {
        const float4 bv0 = *(const float4*)&bias[c_lo];
        const float4 bv1 = *(const float4*)&bias[64 + c_lo];
#pragma unroll
        for (int i = 0; i < 8; ++i) {
            acc[i][0] = bv0.x; acc[i][1] = bv0.y; acc[i][2] = bv0.z; acc[i][3] = bv0.w;
            acc[i][4] = bv1.x; acc[i][5] = bv1.y; acc[i][6] = bv1.z; acc[i][7] = bv1.w;
        }
    }

    const float4* W4 = (const float4*)W;

    for (int kp = 0; kp < 4; ++kp) {
        if (IN_BF16) {
            const uint4* A16 = (const uint4*)Ain;
#pragma unroll
            for (int j = 0; j < 2; ++j) {
                const int l = t + j * 256;
                const int row = l >> 2, ch = l & 3;
                const int rr = row0 + row;
                uint4 v = make_uint4(0u, 0u, 0u, 0u);
                if (rr < n) v = A16[(size_t)rr * 16 + kp * 4 + ch];
                float f[8];
                unpack_bf16x8(v, f);
                float* dst = &as[row * 36 + ch * 8];
                *(float4*)&dst[0] = make_float4(f[0], f[1], f[2], f[3]);
                *(float4*)&dst[4] = make_float4(f[4], f[5], f[6], f[7]);
            }
        } else {
            const float4* A4 = (const float4*)Ain;
#pragma unroll
            for (int j = 0; j < 4; ++j) {
                const int l = t + j * 256;
                const int row = l >> 3, k4 = l & 7;
                const int rr = row0 + row;
                float4 v = make_float4(0.f, 0.f, 0.f, 0.f);
                if (rr < n) v = A4[(size_t)rr * 32 + kp * 8 + k4];
                *(float4*)&as[row * 36 + k4 * 4] = v;
            }
        }
#pragma unroll
        for (int j = 0; j < 4; ++j) {
            const int l = t + j * 256;
            const int k = l >> 5, c4 = l & 31;
            *(float4*)&bs[k * 128 + c4 * 4] = W4[(size_t)(kp * 32 + k) * 32 + c4];
        }
        __syncthreads();

#pragma unroll 2
        for (int kk = 0; kk < 32; kk += 4) {
            float4 a[8], b0[4], b1[4];
#pragma unroll
            for (int i = 0; i < 4; ++i) {
                a[i]     = *(const float4*)&as[(r_lo + i) * 36 + kk];
                a[4 + i] = *(const float4*)&as[(64 + r_lo + i) * 36 + kk];
            }
#pragma unroll
            for (int q = 0; q < 4; ++q) {
                b0[q] = *(const float4*)&bs[(kk + q) * 128 + c_lo];
                b1[q] = *(const float4*)&bs[(kk + q) * 128 + 64 + c_lo];
            }
#pragma unroll
            for (int q = 0; q < 4; ++q) {
#pragma unroll
                for (int i = 0; i < 8; ++i) {
                    const float av = f4c(a[i], q);
                    acc[i][0] = fmaf(av, b0[q].x, acc[i][0]);
                    acc[i][1] = fmaf(av, b0[q].y, acc[i][1]);
                    acc[i][2] = fmaf(av, b0[q].z, acc[i][2]);
                    acc[i][3] = fmaf(av, b0[q].w, acc[i][3]);
                    acc[i][4] = fmaf(av, b1[q].x, acc[i][4]);
                    acc[i][5] = fmaf(av, b1[q].y, acc[i][5]);
                    acc[i][6] = fmaf(av, b1[q].z, acc[i][6]);
                    acc[i][7] = fmaf(av, b1[q].w, acc[i][7]);
                }
            }
        }
        __syncthreads();
    }

#pragma unroll
    for (int i = 0; i < 8; ++i) {
        const int lr = (i < 4) ? (r_lo + i) : (64 + r_lo + i - 4);
        const int rr = row0 + lr;
        if (rr < n) {
            uint2 lo = make_uint2(pack_bf16x2(acc[i][0], acc[i][1]),
                                  pack_bf16x2(acc[i][2], acc[i][3]));
            uint2 hi = make_uint2(pack_bf16x2(acc[i][4], acc[i][5]),
                                  pack_bf16x2(acc[i][6], acc[i][7]));
            *(uint2*)&Yb[(size_t)rr * DIM + c_lo] = lo;
            *(uint2*)&Yb[(size_t)rr * DIM + 64 + c_lo] = hi;
        }
    }
}

// ---------------- CSR build, two-level ----------------
// Pass 1: bin edges by bucket (row>>8). 391 sequential write streams -> the
// active L2 write frontier is ~391 lines; each 64B line fills before eviction
// (vs 100k row-streams previously: 8x write amplification).
__global__ __launch_bounds__(256) void pass1_bin(const int* __restrict__ rows,
                                                 const int* __restrict__ cols,
                                                 const float* __restrict__ vals,
                                                 int* __restrict__ bcnt,
                                                 int2* __restrict__ tmp, int nnz) {
    const int e = blockIdx.x * blockDim.x + threadIdx.x;
    if (e >= nnz) return;
    const int r = rows[e];
    const int b = r >> 8;
    const int rl = r & 255;
    const int pos = atomicAdd(&bcnt[b], 1);
    if (pos < BCAP)
        tmp[(size_t)b * BCAP + pos] = make_int2((rl << 24) | cols[e], __float_as_int(vals[e]));
}

// Exclusive scan of the 391 bucket counts (single block).
__global__ __launch_bounds__(512) void scan_buckets(const int* __restrict__ bcnt,
                                                    int* __restrict__ bbase, int nb) {
    __shared__ int s[512];
    const int t = threadIdx.x;
    const int v = (t < nb) ? bcnt[t] : 0;
    s[t] = v;
    __syncthreads();
    for (int off = 1; off < 512; off <<= 1) {
        int x = (t >= off) ? s[t - off] : 0;
        __syncthreads();
        s[t] += x;
        __syncthreads();
    }
    if (t < nb) bbase[t] = s[t] - v;
}

// Pass 2: one block per bucket. LDS row-histogram -> LDS scan -> exact scatter
// into the bucket's contiguous ~32KB CSR window (L2-resident while hot).
// Also emits row_ptr / counts (replaces hist_rows + 3 scan kernels).
__global__ __launch_bounds__(256) void pass2_sort(const int2* __restrict__ tmp,
                                                  const int* __restrict__ bcnt,
                                                  const int* __restrict__ bbase,
                                                  int2* __restrict__ epack,
                                                  int* __restrict__ row_ptr,
                                                  int* __restrict__ counts, int n) {
    __shared__ int cnt[256];
    __shared__ int s[256];
    __shared__ int cur[256];
    const int b = blockIdx.x;
    const int t = threadIdx.x;
    const int row0 = b * BROWS;
    const int nrows = min(BROWS, n - row0);
    const int m = min(bcnt[b], BCAP);
    const int base = bbase[b];
    const int2* __restrict__ src = tmp + (size_t)b * BCAP;

    cnt[t] = 0;
    __syncthreads();
    for (int i = t; i < m; i += 256)
        atomicAdd(&cnt[((unsigned)src[i].x) >> 24], 1);
    __syncthreads();

    const int v = cnt[t];
    s[t] = v;
    __syncthreads();
    for (int off = 1; off < 256; off <<= 1) {
        int x = (t >= off) ? s[t - off] : 0;
        __syncthreads();
        s[t] += x;
        __syncthreads();
    }
    const int excl = s[t] - v;
    if (t < nrows) {
        row_ptr[row0 + t] = base + excl;
        counts[row0 + t] = v;
    }
    cur[t] = base + excl;
    __syncthreads();

    for (int i = t; i < m; i += 256) {
        const int2 e = src[i];
        const int rl = ((unsigned)e.x) >> 24;
        const int pos = atomicAdd(&cur[rl], 1);
        epack[pos] = make_int2(e.x & 0xFFFFFF, e.y);
    }
}

// ---------------- SpMM: out[r] = sum_j v_j * Xb[c_j]  (bf16 gather) ----------------
template <bool RELU_OUT, bool OUT_BF16>
__global__ __launch_bounds__(256) void spmm_csr(const int* __restrict__ row_ptr,
                                                const int* __restrict__ counts,
                                                const int2* __restrict__ epack,
                                                const unsigned short* __restrict__ Xb,
                                                void* __restrict__ out, int n) {
    const int gid = blockIdx.x * blockDim.x + threadIdx.x;
    const int r = gid >> 4;
    const int lane = gid & 15;
    if (r >= n) return;
    const int start = row_ptr[r];
    const int cnt = counts[r];
    const uint4* __restrict__ X16 = (const uint4*)Xb;
    const int2* __restrict__ ep = epack + start;

    float acc[8];
#pragma unroll
    for (int k = 0; k < 8; ++k) acc[k] = 0.f;

    int j = 0;
    for (; j + 4 <= cnt; j += 4) {
        const int2 e0 = ep[j], e1 = ep[j + 1], e2 = ep[j + 2], e3 = ep[j + 3];
        const uint4 x0 = X16[(size_t)e0.x * 16 + lane];
        const uint4 x1 = X16[(size_t)e1.x * 16 + lane];
        const uint4 x2 = X16[(size_t)e2.x * 16 + lane];
        const uint4 x3 = X16[(size_t)e3.x * 16 + lane];
        const float v0 = __int_as_float(e0.y), v1 = __int_as_float(e1.y);
        const float v2 = __int_as_float(e2.y), v3 = __int_as_float(e3.y);
        float f0[8], f1[8], f2[8], f3[8];
        unpack_bf16x8(x0, f0); unpack_bf16x8(x1, f1);
        unpack_bf16x8(x2, f2); unpack_bf16x8(x3, f3);
#pragma unroll
        for (int k = 0; k < 8; ++k)
            acc[k] += v0 * f0[k] + v1 * f1[k] + v2 * f2[k] + v3 * f3[k];
    }
    for (; j < cnt; ++j) {
        const int2 e = ep[j];
        const uint4 x = X16[(size_t)e.x * 16 + lane];
        const float v = __int_as_float(e.y);
        float f[8];
        unpack_bf16x8(x, f);
#pragma unroll
        for (int k = 0; k < 8; ++k) acc[k] += v * f[k];
    }

    if (RELU_OUT) {
#pragma unroll
        for (int k = 0; k < 8; ++k) acc[k] = fmaxf(acc[k], 0.f);
    }

    if (OUT_BF16) {
        uint4 pv = make_uint4(pack_bf16x2(acc[0], acc[1]), pack_bf16x2(acc[2], acc[3]),
                              pack_bf16x2(acc[4], acc[5]), pack_bf16x2(acc[6], acc[7]));
        ((uint4*)out)[(size_t)r * 16 + lane] = pv;
    } else {
        float* of = (float*)out;
        *(float4*)&of[(size_t)r * DIM + lane * 8]     = make_float4(acc[0], acc[1], acc[2], acc[3]);
        *(float4*)&of[(size_t)r * DIM + lane * 8 + 4] = make_float4(acc[4], acc[5], acc[6], acc[7]);
    }
}

extern "C" void kernel_launch(void* const* d_in, const int* in_sizes, int n_in,
                              void* d_out, int out_size, void* d_ws, size_t ws_size,
                              hipStream_t stream) {
    const float* X      = (const float*)d_in[0];
    const int*   H_rows = (const int*)d_in[1];
    const int*   H_cols = (const int*)d_in[2];
    const float* H_vals = (const float*)d_in[3];
    const float* W1     = (const float*)d_in[4];
    const float* b1     = (const float*)d_in[5];
    const float* W2     = (const float*)d_in[6];
    const float* b2     = (const float*)d_in[7];
    float* out = (float*)d_out;

    const int E = in_sizes[1];
    const int N = NNODES;
    const size_t bmat_bytes = (size_t)N * DIM * 2;

    const int gemm_blocks = (N + 127) / 128;
    const int eblocks = (E + 255) / 256;
    const int spmm_blocks = (N * 16 + 255) / 256;

    // Workspace layout (~81 MB)
    char* p = (char*)d_ws;
    unsigned short* Yb = (unsigned short*)p;  p += bmat_bytes;              // 25.6 MB
    unsigned short* hb = (unsigned short*)p;  p += bmat_bytes;              // 25.6 MB
    int2* epack        = (int2*)p;            p += (size_t)E * 8;           // 12.8 MB
    int2* tmp          = (int2*)p;            p += (size_t)NB * BCAP * 8;   // 16.0 MB
    int*  bcnt         = (int*)p;             p += (size_t)NB * 4;
    int*  bbase        = (int*)p;             p += (size_t)NB * 4;
    int*  row_ptr      = (int*)p;             p += (size_t)N * 4;
    int*  counts       = (int*)p;             p += (size_t)N * 4;

    // ---- CSR build ----
    hipMemsetAsync(bcnt, 0, (size_t)NB * 4, stream);
    pass1_bin<<<eblocks, 256, 0, stream>>>(H_rows, H_cols, H_vals, bcnt, tmp, E);
    scan_buckets<<<1, 512, 0, stream>>>(bcnt, bbase, NB);
    pass2_sort<<<NB, 256, 0, stream>>>(tmp, bcnt, bbase, epack, row_ptr, counts, N);

    // Layer 1: Yb = X @ W1 + b1 (bf16); hb = relu(H @ Yb) (bf16)
    gemm_tile<false><<<gemm_blocks, 256, 0, stream>>>(X, W1, b1, Yb, N);
    spmm_csr<true, true><<<spmm_blocks, 256, 0, stream>>>(row_ptr, counts, epack, Yb, hb, N);

    // Layer 2: Yb = hb @ W2 + b2 (bf16); out = H @ Yb (fp32)
    gemm_tile<true><<<gemm_blocks, 256, 0, stream>>>(hb, W2, b2, Yb, N);
    spmm_csr<false, false><<<spmm_blocks, 256, 0, stream>>>(row_ptr, counts, epack, Yb, out, N);
}

// Round 6
// 395.273 us; speedup vs baseline: 2.3193x; 2.3193x over previous
//
#include <hip/hip_runtime.h>

#define NNODES 100000
#define DIM 128
#define BROWS 256               // rows per bucket
#define NB ((NNODES + BROWS - 1) / BROWS)   // 391 buckets
#define BCAP 5120               // capacity per bucket (mean 4096, sd 64 -> +16 sigma)
#define CHUNK 4096              // edges per pass1 block

__device__ __forceinline__ float f4c(const float4& v, int q) {
    switch (q) { case 0: return v.x; case 1: return v.y; case 2: return v.z; }
    return v.w;
}

__device__ __forceinline__ unsigned int pack_bf16x2(float lo, float hi) {
    unsigned int ul = __float_as_uint(lo);
    unsigned int uh = __float_as_uint(hi);
    ul = (ul + 0x7fffu + ((ul >> 16) & 1u)) >> 16;   // RNE
    uh = (uh + 0x7fffu + ((uh >> 16) & 1u)) & 0xffff0000u;
    return uh | ul;
}

__device__ __forceinline__ void unpack_bf16x8(uint4 v, float* f) {
    f[0] = __uint_as_float(v.x << 16); f[1] = __uint_as_float(v.x & 0xffff0000u);
    f[2] = __uint_as_float(v.y << 16); f[3] = __uint_as_float(v.y & 0xffff0000u);
    f[4] = __uint_as_float(v.z << 16); f[5] = __uint_as_float(v.z & 0xffff0000u);
    f[6] = __uint_as_float(v.w << 16); f[7] = __uint_as_float(v.w & 0xffff0000u);
}

// ---------------- Dense GEMM: Yb(bf16) = A @ W + b ----------------
template <bool IN_BF16>
__global__ __launch_bounds__(256, 2) void gemm_tile(const void* __restrict__ Ain,
                                                    const float* __restrict__ W,
                                                    const float* __restrict__ bias,
                                                    unsigned short* __restrict__ Yb, int n) {
    __shared__ float as[128 * 36];
    __shared__ float bs[32 * 128];
    const int t = threadIdx.x;
    const int tx = t & 15, ty = t >> 4;
    const int row0 = blockIdx.x * 128;
    const int r_lo = ty * 4;
    const int c_lo = tx * 4;

    float acc[8][8];
    {
        const float4 bv0 = *(const float4*)&bias[c_lo];
        const float4 bv1 = *(const float4*)&bias[64 + c_lo];
#pragma unroll
        for (int i = 0; i < 8; ++i) {
            acc[i][0] = bv0.x; acc[i][1] = bv0.y; acc[i][2] = bv0.z; acc[i][3] = bv0.w;
            acc[i][4] = bv1.x; acc[i][5] = bv1.y; acc[i][6] = bv1.z; acc[i][7] = bv1.w;
        }
    }

    const float4* W4 = (const float4*)W;

    for (int kp = 0; kp < 4; ++kp) {
        if (IN_BF16) {
            const uint4* A16 = (const uint4*)Ain;
#pragma unroll
            for (int j = 0; j < 2; ++j) {
                const int l = t + j * 256;
                const int row = l >> 2, ch = l & 3;
                const int rr = row0 + row;
                uint4 v = make_uint4(0u, 0u, 0u, 0u);
                if (rr < n) v = A16[(size_t)rr * 16 + kp * 4 + ch];
                float f[8];
                unpack_bf16x8(v, f);
                float* dst = &as[row * 36 + ch * 8];
                *(float4*)&dst[0] = make_float4(f[0], f[1], f[2], f[3]);
                *(float4*)&dst[4] = make_float4(f[4], f[5], f[6], f[7]);
            }
        } else {
            const float4* A4 = (const float4*)Ain;
#pragma unroll
            for (int j = 0; j < 4; ++j) {
                const int l = t + j * 256;
                const int row = l >> 3, k4 = l & 7;
                const int rr = row0 + row;
                float4 v = make_float4(0.f, 0.f, 0.f, 0.f);
                if (rr < n) v = A4[(size_t)rr * 32 + kp * 8 + k4];
                *(float4*)&as[row * 36 + k4 * 4] = v;
            }
        }
#pragma unroll
        for (int j = 0; j < 4; ++j) {
            const int l = t + j * 256;
            const int k = l >> 5, c4 = l & 31;
            *(float4*)&bs[k * 128 + c4 * 4] = W4[(size_t)(kp * 32 + k) * 32 + c4];
        }
        __syncthreads();

#pragma unroll 2
        for (int kk = 0; kk < 32; kk += 4) {
            float4 a[8], b0[4], b1[4];
#pragma unroll
            for (int i = 0; i < 4; ++i) {
                a[i]     = *(const float4*)&as[(r_lo + i) * 36 + kk];
                a[4 + i] = *(const float4*)&as[(64 + r_lo + i) * 36 + kk];
            }
#pragma unroll
            for (int q = 0; q < 4; ++q) {
                b0[q] = *(const float4*)&bs[(kk + q) * 128 + c_lo];
                b1[q] = *(const float4*)&bs[(kk + q) * 128 + 64 + c_lo];
            }
#pragma unroll
            for (int q = 0; q < 4; ++q) {
#pragma unroll
                for (int i = 0; i < 8; ++i) {
                    const float av = f4c(a[i], q);
                    acc[i][0] = fmaf(av, b0[q].x, acc[i][0]);
                    acc[i][1] = fmaf(av, b0[q].y, acc[i][1]);
                    acc[i][2] = fmaf(av, b0[q].z, acc[i][2]);
                    acc[i][3] = fmaf(av, b0[q].w, acc[i][3]);
                    acc[i][4] = fmaf(av, b1[q].x, acc[i][4]);
                    acc[i][5] = fmaf(av, b1[q].y, acc[i][5]);
                    acc[i][6] = fmaf(av, b1[q].z, acc[i][6]);
                    acc[i][7] = fmaf(av, b1[q].w, acc[i][7]);
                }
            }
        }
        __syncthreads();
    }

#pragma unroll
    for (int i = 0; i < 8; ++i) {
        const int lr = (i < 4) ? (r_lo + i) : (64 + r_lo + i - 4);
        const int rr = row0 + lr;
        if (rr < n) {
            uint2 lo = make_uint2(pack_bf16x2(acc[i][0], acc[i][1]),
                                  pack_bf16x2(acc[i][2], acc[i][3]));
            uint2 hi = make_uint2(pack_bf16x2(acc[i][4], acc[i][5]),
                                  pack_bf16x2(acc[i][6], acc[i][7]));
            *(uint2*)&Yb[(size_t)rr * DIM + c_lo] = lo;
            *(uint2*)&Yb[(size_t)rr * DIM + 64 + c_lo] = hi;
        }
    }
}

// ---------------- CSR build, two-level ----------------
// Pass 1 (v2): per-block LDS histogram -> ONE global atomic per (block,bucket)
// to reserve a contiguous range -> contiguous scatter. Fixes round-5's
// same-address atomic serialization (1.6M atomics on 391 addresses) AND
// round-4's partial-line write amplification: each block writes ~84B
// contiguous per bucket.
__global__ __launch_bounds__(256) void pass1_bin(const int* __restrict__ rows,
                                                 const int* __restrict__ cols,
                                                 const float* __restrict__ vals,
                                                 int* __restrict__ bcnt,
                                                 int2* __restrict__ tmp, int nnz) {
    __shared__ int hist[NB];
    __shared__ int base[NB];
    __shared__ int cur[NB];
    const int t = threadIdx.x;
    const int e0 = blockIdx.x * CHUNK;
    const int e1 = min(e0 + CHUNK, nnz);

    for (int i = t; i < NB; i += 256) { hist[i] = 0; cur[i] = 0; }
    __syncthreads();

    for (int i = e0 + t; i < e1; i += 256)
        atomicAdd(&hist[rows[i] >> 8], 1);
    __syncthreads();

    for (int i = t; i < NB; i += 256)
        base[i] = (hist[i] > 0) ? atomicAdd(&bcnt[i], hist[i]) : 0;
    __syncthreads();

    for (int i = e0 + t; i < e1; i += 256) {
        const int r = rows[i];
        const int b = r >> 8;
        const int pos = base[b] + atomicAdd(&cur[b], 1);
        if (pos < BCAP)
            tmp[(size_t)b * BCAP + pos] =
                make_int2(((r & 255) << 24) | cols[i], __float_as_int(vals[i]));
    }
}

// Exclusive scan of the 391 bucket counts (single block).
__global__ __launch_bounds__(512) void scan_buckets(const int* __restrict__ bcnt,
                                                    int* __restrict__ bbase, int nb) {
    __shared__ int s[512];
    const int t = threadIdx.x;
    const int v = (t < nb) ? bcnt[t] : 0;
    s[t] = v;
    __syncthreads();
    for (int off = 1; off < 512; off <<= 1) {
        int x = (t >= off) ? s[t - off] : 0;
        __syncthreads();
        s[t] += x;
        __syncthreads();
    }
    if (t < nb) bbase[t] = s[t] - v;
}

// Pass 2: one block per bucket. LDS row-histogram -> LDS scan -> exact scatter
// into the bucket's contiguous ~32KB CSR window. Emits row_ptr / counts.
__global__ __launch_bounds__(256) void pass2_sort(const int2* __restrict__ tmp,
                                                  const int* __restrict__ bcnt,
                                                  const int* __restrict__ bbase,
                                                  int2* __restrict__ epack,
                                                  int* __restrict__ row_ptr,
                                                  int* __restrict__ counts, int n) {
    __shared__ int cnt[256];
    __shared__ int s[256];
    __shared__ int cur[256];
    const int b = blockIdx.x;
    const int t = threadIdx.x;
    const int row0 = b * BROWS;
    const int nrows = min(BROWS, n - row0);
    const int m = min(bcnt[b], BCAP);
    const int base = bbase[b];
    const int2* __restrict__ src = tmp + (size_t)b * BCAP;

    cnt[t] = 0;
    __syncthreads();
    for (int i = t; i < m; i += 256)
        atomicAdd(&cnt[((unsigned)src[i].x) >> 24], 1);
    __syncthreads();

    const int v = cnt[t];
    s[t] = v;
    __syncthreads();
    for (int off = 1; off < 256; off <<= 1) {
        int x = (t >= off) ? s[t - off] : 0;
        __syncthreads();
        s[t] += x;
        __syncthreads();
    }
    const int excl = s[t] - v;
    if (t < nrows) {
        row_ptr[row0 + t] = base + excl;
        counts[row0 + t] = v;
    }
    cur[t] = base + excl;
    __syncthreads();

    for (int i = t; i < m; i += 256) {
        const int2 e = src[i];
        const int rl = ((unsigned)e.x) >> 24;
        const int pos = atomicAdd(&cur[rl], 1);
        epack[pos] = make_int2(e.x & 0xFFFFFF, e.y);
    }
}

// ---------------- SpMM: out[r] = sum_j v_j * Xb[c_j]  (bf16 gather) ----------------
template <bool RELU_OUT, bool OUT_BF16>
__global__ __launch_bounds__(256) void spmm_csr(const int* __restrict__ row_ptr,
                                                const int* __restrict__ counts,
                                                const int2* __restrict__ epack,
                                                const unsigned short* __restrict__ Xb,
                                                void* __restrict__ out, int n) {
    const int gid = blockIdx.x * blockDim.x + threadIdx.x;
    const int r = gid >> 4;
    const int lane = gid & 15;
    if (r >= n) return;
    const int start = row_ptr[r];
    const int cnt = counts[r];
    const uint4* __restrict__ X16 = (const uint4*)Xb;
    const int2* __restrict__ ep = epack + start;

    float acc[8];
#pragma unroll
    for (int k = 0; k < 8; ++k) acc[k] = 0.f;

    int j = 0;
    for (; j + 4 <= cnt; j += 4) {
        const int2 e0 = ep[j], e1 = ep[j + 1], e2 = ep[j + 2], e3 = ep[j + 3];
        const uint4 x0 = X16[(size_t)e0.x * 16 + lane];
        const uint4 x1 = X16[(size_t)e1.x * 16 + lane];
        const uint4 x2 = X16[(size_t)e2.x * 16 + lane];
        const uint4 x3 = X16[(size_t)e3.x * 16 + lane];
        const float v0 = __int_as_float(e0.y), v1 = __int_as_float(e1.y);
        const float v2 = __int_as_float(e2.y), v3 = __int_as_float(e3.y);
        float f0[8], f1[8], f2[8], f3[8];
        unpack_bf16x8(x0, f0); unpack_bf16x8(x1, f1);
        unpack_bf16x8(x2, f2); unpack_bf16x8(x3, f3);
#pragma unroll
        for (int k = 0; k < 8; ++k)
            acc[k] += v0 * f0[k] + v1 * f1[k] + v2 * f2[k] + v3 * f3[k];
    }
    for (; j < cnt; ++j) {
        const int2 e = ep[j];
        const uint4 x = X16[(size_t)e.x * 16 + lane];
        const float v = __int_as_float(e.y);
        float f[8];
        unpack_bf16x8(x, f);
#pragma unroll
        for (int k = 0; k < 8; ++k) acc[k] += v * f[k];
    }

    if (RELU_OUT) {
#pragma unroll
        for (int k = 0; k < 8; ++k) acc[k] = fmaxf(acc[k], 0.f);
    }

    if (OUT_BF16) {
        uint4 pv = make_uint4(pack_bf16x2(acc[0], acc[1]), pack_bf16x2(acc[2], acc[3]),
                              pack_bf16x2(acc[4], acc[5]), pack_bf16x2(acc[6], acc[7]));
        ((uint4*)out)[(size_t)r * 16 + lane] = pv;
    } else {
        float* of = (float*)out;
        *(float4*)&of[(size_t)r * DIM + lane * 8]     = make_float4(acc[0], acc[1], acc[2], acc[3]);
        *(float4*)&of[(size_t)r * DIM + lane * 8 + 4] = make_float4(acc[4], acc[5], acc[6], acc[7]);
    }
}

extern "C" void kernel_launch(void* const* d_in, const int* in_sizes, int n_in,
                              void* d_out, int out_size, void* d_ws, size_t ws_size,
                              hipStream_t stream) {
    const float* X      = (const float*)d_in[0];
    const int*   H_rows = (const int*)d_in[1];
    const int*   H_cols = (const int*)d_in[2];
    const float* H_vals = (const float*)d_in[3];
    const float* W1     = (const float*)d_in[4];
    const float* b1     = (const float*)d_in[5];
    const float* W2     = (const float*)d_in[6];
    const float* b2     = (const float*)d_in[7];
    float* out = (float*)d_out;

    const int E = in_sizes[1];
    const int N = NNODES;
    const size_t bmat_bytes = (size_t)N * DIM * 2;

    const int gemm_blocks = (N + 127) / 128;
    const int p1_blocks = (E + CHUNK - 1) / CHUNK;
    const int spmm_blocks = (N * 16 + 255) / 256;

    // Workspace layout (~81 MB)
    char* p = (char*)d_ws;
    unsigned short* Yb = (unsigned short*)p;  p += bmat_bytes;              // 25.6 MB
    unsigned short* hb = (unsigned short*)p;  p += bmat_bytes;              // 25.6 MB
    int2* epack        = (int2*)p;            p += (size_t)E * 8;           // 12.8 MB
    int2* tmp          = (int2*)p;            p += (size_t)NB * BCAP * 8;   // 16.0 MB
    int*  bcnt         = (int*)p;             p += (size_t)NB * 4;
    int*  bbase        = (int*)p;             p += (size_t)NB * 4;
    int*  row_ptr      = (int*)p;             p += (size_t)N * 4;
    int*  counts       = (int*)p;             p += (size_t)N * 4;

    // ---- CSR build ----
    hipMemsetAsync(bcnt, 0, (size_t)NB * 4, stream);
    pass1_bin<<<p1_blocks, 256, 0, stream>>>(H_rows, H_cols, H_vals, bcnt, tmp, E);
    scan_buckets<<<1, 512, 0, stream>>>(bcnt, bbase, NB);
    pass2_sort<<<NB, 256, 0, stream>>>(tmp, bcnt, bbase, epack, row_ptr, counts, N);

    // Layer 1: Yb = X @ W1 + b1 (bf16); hb = relu(H @ Yb) (bf16)
    gemm_tile<false><<<gemm_blocks, 256, 0, stream>>>(X, W1, b1, Yb, N);
    spmm_csr<true, true><<<spmm_blocks, 256, 0, stream>>>(row_ptr, counts, epack, Yb, hb, N);

    // Layer 2: Yb = hb @ W2 + b2 (bf16); out = H @ Yb (fp32)
    gemm_tile<true><<<gemm_blocks, 256, 0, stream>>>(hb, W2, b2, Yb, N);
    spmm_csr<false, false><<<spmm_blocks, 256, 0, stream>>>(row_ptr, counts, epack, Yb, out, N);
}